// Round 7
// baseline (266.413 us; speedup 1.0000x reference)
//
#include <hip/hip_runtime.h>
#include <hip/hip_bf16.h>
#include <math.h>

#define DEVINL __device__ __forceinline__

typedef __attribute__((ext_vector_type(4))) float f32x4;
typedef __attribute__((ext_vector_type(8))) short s16x8;

DEVINL unsigned short f2bf(float f) {
  union { float f; unsigned u; } v; v.f = f;
  unsigned r = v.u + 0x7FFFu + ((v.u >> 16) & 1u);   // round-to-nearest-even
  return (unsigned short)(r >> 16);
}
DEVINL float bf2f(unsigned short s) {
  union { unsigned u; float f; } v; v.u = ((unsigned)s) << 16;
  return v.f;
}
DEVINL float gelu_exact(float x) {
  return 0.5f * x * (1.0f + erff(x * 0.70710678118654752f));
}

// ---------------------------------------------------------------------------
// x (f32) -> bf16 hi + bf16 lo (split for fp32-class MFMA sim)
// ---------------------------------------------------------------------------
__global__ __launch_bounds__(256) void conv_kernel(const float* __restrict__ x,
                                                   unsigned short* __restrict__ xh,
                                                   unsigned short* __restrict__ xl) {
  int i = blockIdx.x * 256 + threadIdx.x;   // float4 units, grid sized exactly
  float4 v = ((const float4*)x)[i];
  float f[4] = {v.x, v.y, v.z, v.w};
  unsigned short h[4], l[4];
#pragma unroll
  for (int j = 0; j < 4; ++j) {
    h[j] = f2bf(f[j]);
    l[j] = f2bf(f[j] - bf2f(h[j]));
  }
  uint2 uh, ul;
  uh.x = (unsigned)h[0] | ((unsigned)h[1] << 16);
  uh.y = (unsigned)h[2] | ((unsigned)h[3] << 16);
  ul.x = (unsigned)l[0] | ((unsigned)l[1] << 16);
  ul.y = (unsigned)l[2] | ((unsigned)l[3] << 16);
  ((uint2*)xh)[i] = uh;
  ((uint2*)xl)[i] = ul;
}

// ---------------------------------------------------------------------------
// Fused sim = x@x^T (split-bf16, 3 MFMA passes) + top-9 per row.
// R6 post-mortem: with DYNAMIC LDS the compiler sees 0 bytes of LDS and
// targets 8 waves/EU -> VGPR capped at 64 -> ~2.3MB scratch spill of hot
// state (waves_per_eu attr couldn't override it; R4's (2,2)+VGPR=88-clean
// vs R5/R6's 64-spilled confirms the heuristic). Fix: STATIC __shared__
// (57,472B) so the backend derives the LDS-limited occupancy itself
// (2 wg/CU = 4 waves/EU -> 128-VGPR budget >= ~90 demand -> no spill).
// ---------------------------------------------------------------------------
__global__ __launch_bounds__(512)
#if __has_attribute(amdgpu_waves_per_eu)
__attribute__((amdgpu_waves_per_eu(4, 4)))
#endif
void simtopk_kernel(const unsigned short* __restrict__ xh,
                    const unsigned short* __restrict__ xl,
                    int* __restrict__ graph) {
  const int tid  = threadIdx.x;
  const int lane = tid & 63;
  const int w    = tid >> 6;
  const int rb   = blockIdx.x;       // 0..31, 32 rows each
  const int b    = blockIdx.y;
  const int wm   = w >> 2, wn = w & 3;

  __shared__ __align__(16) char smem[57472];                // STATIC: compiler sees LDS
  unsigned short* colsH = (unsigned short*)smem;            // [64][192] linear, 24576B
  unsigned short* colsL = (unsigned short*)(smem + 24576);  // [64][192] linear
  float* simt = (float*)(smem + 49152);                     // [32][65] f32, 8320B
  // merge-phase aliases (cols/simt dead by then):
  float* Lv = (float*)smem;                                 // [512][9] f32
  int*   Li = (int*)(smem + 18432);                         // [512][9]
  float* Mv = (float*)(smem + 36864);                       // [128][9] f32
  int*   Mi = (int*)(smem + 41472);                         // [128][9]

  const unsigned short* xhb = xh + (size_t)b * (1024 * 192);
  const unsigned short* xlb = xl + (size_t)b * (1024 * 192);

  // A fragments (rows) -> registers, loaded once. 48 VGPR.
  s16x8 ah[6], al[6];
#pragma unroll
  for (int ks = 0; ks < 6; ++ks) {
    int r = rb * 32 + wm * 16 + (lane & 15);
    size_t off = (size_t)r * 192 + ks * 32 + (lane >> 4) * 8;
    ah[ks] = *(const s16x8*)(xhb + off);
    al[ks] = *(const s16x8*)(xlb + off);
  }

  // Stage col tile ct (64 rows x 192) into LDS. Source pre-swizzled
  // (chunk ^= row&7), LDS dest linear (global_load_lds constraint).
  auto stage = [&](int ct) {
#pragma unroll
    for (int i = 0; i < 3; ++i) {
      int c = tid + i * 512;                 // 16B-chunk id, 0..1535
      int row = c / 24, cc = c - row * 24;
      size_t goff = (size_t)(ct * 64 + row) * 192 + (size_t)((cc ^ (row & 7)) * 8);
      unsigned short* dstH = colsH + (size_t)c * 8;   // wave-uniform base + lane*16B
      unsigned short* dstL = colsL + (size_t)c * 8;
      __builtin_amdgcn_global_load_lds((const __attribute__((address_space(1))) void*)(xhb + goff),
                                       (__attribute__((address_space(3))) void*)dstH, 16, 0, 0);
      __builtin_amdgcn_global_load_lds((const __attribute__((address_space(1))) void*)(xlb + goff),
                                       (__attribute__((address_space(3))) void*)dstL, 16, 0, 0);
    }
  };

  float tv[9]; int tix[9];
#pragma unroll
  for (int k = 0; k < 9; ++k) { tv[k] = -3.0e38f; tix[k] = 1 << 30; }

  stage(0);
  __syncthreads();

  for (int ct = 0; ct < 16; ++ct) {
    f32x4 a0 = 0, a1 = 0, a2 = 0;

#pragma unroll
    for (int ks = 0; ks < 6; ++ks) {
      const int chk = ks * 4 + (lane >> 4);
      const int rc  = wn * 16 + (lane & 15);
      const int si  = rc * 192 + ((chk ^ (rc & 7)) * 8);
      s16x8 bh = *(const s16x8*)&colsH[si];
      s16x8 bl = *(const s16x8*)&colsL[si];
      a0 = __builtin_amdgcn_mfma_f32_16x16x32_bf16(ah[ks], bh, a0, 0, 0, 0);
      a1 = __builtin_amdgcn_mfma_f32_16x16x32_bf16(ah[ks], bl, a1, 0, 0, 0);
      a2 = __builtin_amdgcn_mfma_f32_16x16x32_bf16(al[ks], bh, a2, 0, 0, 0);
    }

    // write sim tile (C/D: col=lane&15, row=(lane>>4)*4+reg — m89-verified)
#pragma unroll
    for (int r = 0; r < 4; ++r) {
      int rr = wm * 16 + (lane >> 4) * 4 + r;
      int cc = wn * 16 + (lane & 15);
      simt[rr * 65 + cc] = a0[r] + a1[r] + a2[r];
    }
    __syncthreads();   // mfma done reading cols; simt visible

    if (ct < 15) stage(ct + 1);  // async DMA overlaps scan below; drained at next barrier

    // top-9 scan: 16 threads per row, 4 cols each
    {
      int r = tid >> 4, q = tid & 15;
#pragma unroll
      for (int j = 0; j < 4; ++j) {
        float v = simt[r * 65 + q * 4 + j];
        int   c = ct * 64 + q * 4 + j;
        if (v > tv[8]) {   // strict: ascending c keeps lower index first on ties
          tv[8] = v; tix[8] = c;
#pragma unroll
          for (int s = 8; s > 0; --s) {
            if (tv[s] > tv[s - 1]) {
              float fv = tv[s]; tv[s] = tv[s - 1]; tv[s - 1] = fv;
              int   fi = tix[s]; tix[s] = tix[s - 1]; tix[s - 1] = fi;
            }
          }
        }
      }
    }
    __syncthreads();   // scan done; staged loads drained (vmcnt(0) at barrier)
  }

  // dump per-thread lists (cols region dead now)
#pragma unroll
  for (int k = 0; k < 9; ++k) { Lv[tid * 9 + k] = tv[k]; Li[tid * 9 + k] = tix[k]; }
  __syncthreads();

  // merge stage A: 128 threads, each merges 4 of the 16 lists of its row
  if (tid < 128) {
    int r = tid >> 2, p = tid & 3;
    float fv[9]; int fi[9];
#pragma unroll
    for (int k = 0; k < 9; ++k) { fv[k] = -3.0e38f; fi[k] = 1 << 30; }
    for (int s4 = 0; s4 < 4; ++s4) {
      int base = (r * 16 + p * 4 + s4) * 9;
#pragma unroll
      for (int k = 0; k < 9; ++k) {
        float v = Lv[base + k]; int c = Li[base + k];
        bool better = (v > fv[8]) || (v == fv[8] && c < fi[8]);
        if (better) {
          fv[8] = v; fi[8] = c;
#pragma unroll
          for (int s = 8; s > 0; --s) {
            bool up = (fv[s] > fv[s - 1]) || (fv[s] == fv[s - 1] && fi[s] < fi[s - 1]);
            if (up) {
              float a = fv[s]; fv[s] = fv[s - 1]; fv[s - 1] = a;
              int  ii = fi[s]; fi[s] = fi[s - 1]; fi[s - 1] = ii;
            }
          }
        }
      }
    }
#pragma unroll
    for (int k = 0; k < 9; ++k) { Mv[tid * 9 + k] = fv[k]; Mi[tid * 9 + k] = fi[k]; }
  }
  __syncthreads();

  // merge stage B: 32 threads, one per row, merge 4 partials -> graph
  if (tid < 32) {
    float fv[9]; int fi[9];
#pragma unroll
    for (int k = 0; k < 9; ++k) { fv[k] = -3.0e38f; fi[k] = 1 << 30; }
    for (int p = 0; p < 4; ++p) {
      int base = (tid * 4 + p) * 9;
#pragma unroll
      for (int k = 0; k < 9; ++k) {
        float v = Mv[base + k]; int c = Mi[base + k];
        bool better = (v > fv[8]) || (v == fv[8] && c < fi[8]);
        if (better) {
          fv[8] = v; fi[8] = c;
#pragma unroll
          for (int s = 8; s > 0; --s) {
            bool up = (fv[s] > fv[s - 1]) || (fv[s] == fv[s - 1] && fi[s] < fi[s - 1]);
            if (up) {
              float a = fv[s]; fv[s] = fv[s - 1]; fv[s - 1] = a;
              int  ii = fi[s]; fi[s] = fi[s - 1]; fi[s - 1] = ii;
            }
          }
        }
      }
    }
    int* gout = graph + ((size_t)b * 1024 + rb * 32 + tid) * 9;
#pragma unroll
    for (int k = 0; k < 9; ++k) gout[k] = fi[k];
  }
}

// ---------------------------------------------------------------------------
// Gather-max aggregation + interleave: cat[...,2c]=h, cat[...,2c+1]=max_k(h[nbr]-h)
// ---------------------------------------------------------------------------
__global__ __launch_bounds__(256) void agg_kernel(const unsigned short* __restrict__ h,
                                                  const int* __restrict__ graph,
                                                  unsigned short* __restrict__ cat) {
  int gid  = blockIdx.x * 4 + (threadIdx.x >> 6);
  int lane = threadIdx.x & 63;
  int b = gid >> 10;
  int n = gid & 1023;
  const unsigned short* hb = h + (size_t)b * (1024 * 192);
  const int* g = graph + (size_t)gid * 9;
  float hn[3];
#pragma unroll
  for (int j = 0; j < 3; ++j) hn[j] = bf2f(hb[(size_t)n * 192 + lane + j * 64]);
  float ag[3] = {-3.0e38f, -3.0e38f, -3.0e38f};
  for (int k = 0; k < 9; ++k) {
    int idx = g[k];
#pragma unroll
    for (int j = 0; j < 3; ++j) {
      float v = bf2f(hb[(size_t)idx * 192 + lane + j * 64]) - hn[j];
      ag[j] = fmaxf(ag[j], v);
    }
  }
  unsigned* crow = (unsigned*)cat + (size_t)gid * 192;
#pragma unroll
  for (int j = 0; j < 3; ++j) {
    int c = lane + j * 64;
    crow[c] = (unsigned)f2bf(hn[j]) | ((unsigned)f2bf(ag[j]) << 16);
  }
}

// ---------------------------------------------------------------------------
// NT GEMM: out[m,n] = epi( sum_k A[m,k]*W[n,k] + bias[n] )
// A bf16 [M,K], W f32 [N,K] (converted to bf16 in staging). BM=128 BN=64 BK=64.
// ---------------------------------------------------------------------------
template <bool GELU_, bool RESID>
__global__ __launch_bounds__(256) void gemm_kernel(const unsigned short* __restrict__ A,
                                                   const float* __restrict__ W,
                                                   const float* __restrict__ bias,
                                                   const float* __restrict__ resid,
                                                   unsigned short* __restrict__ outb,
                                                   float* __restrict__ outf,
                                                   int N, int K) {
  __shared__ unsigned short As[2][128 * 64];
  __shared__ unsigned short Ws[2][64 * 64];

  const int tid  = threadIdx.x;
  const int lane = tid & 63;
  const int w    = tid >> 6;
  const int m0   = blockIdx.x * 128;
  const int n0   = blockIdx.y * 64;

  auto stageA = [&](int buf, int kt) {
    const unsigned short* gA = A + (size_t)m0 * K + kt * 64;
#pragma unroll
    for (int i = 0; i < 4; ++i) {
      int chunk = w * 4 + i;                                   // 1KB chunk = 8 rows
      const unsigned short* src = gA + (size_t)(chunk * 8 + (lane >> 3)) * K + (lane & 7) * 8;
      unsigned short* dst = &As[buf][chunk * 512];             // wave-uniform base
      __builtin_amdgcn_global_load_lds((const __attribute__((address_space(1))) void*)src,
                                       (__attribute__((address_space(3))) void*)dst, 16, 0, 0);
    }
  };
  auto stageW = [&](int buf, int kt) {
#pragma unroll
    for (int i = 0; i < 4; ++i) {
      int idx = tid + i * 256;                                 // 0..1023
      int n = idx >> 4, kq = idx & 15;
      float4 v = *(const float4*)(W + (size_t)(n0 + n) * K + kt * 64 + kq * 4);
      uint2 u;
      u.x = (unsigned)f2bf(v.x) | ((unsigned)f2bf(v.y) << 16);
      u.y = (unsigned)f2bf(v.z) | ((unsigned)f2bf(v.w) << 16);
      *(uint2*)&Ws[buf][n * 64 + kq * 4] = u;
    }
  };

  stageA(0, 0);
  stageW(0, 0);
  __syncthreads();

  const int wm = w >> 1, wn = w & 1;
  f32x4 acc[4][2];
#pragma unroll
  for (int a = 0; a < 4; ++a)
#pragma unroll
    for (int c = 0; c < 2; ++c) acc[a][c] = 0;

  const int nk = K >> 6;
  for (int kt = 0; kt < nk; ++kt) {
    const int cur = kt & 1;
    if (kt + 1 < nk) { stageA(cur ^ 1, kt + 1); stageW(cur ^ 1, kt + 1); }
#pragma unroll
    for (int ks = 0; ks < 2; ++ks) {
      const int ko = ks * 32 + (lane >> 4) * 8;
      s16x8 af[4], bfr[2];
#pragma unroll
      for (int m2 = 0; m2 < 4; ++m2)
        af[m2] = *(const s16x8*)&As[cur][(wm * 64 + m2 * 16 + (lane & 15)) * 64 + ko];
#pragma unroll
      for (int n2 = 0; n2 < 2; ++n2)
        bfr[n2] = *(const s16x8*)&Ws[cur][(wn * 32 + n2 * 16 + (lane & 15)) * 64 + ko];
#pragma unroll
      for (int m2 = 0; m2 < 4; ++m2)
#pragma unroll
        for (int n2 = 0; n2 < 2; ++n2)
          acc[m2][n2] = __builtin_amdgcn_mfma_f32_16x16x32_bf16(af[m2], bfr[n2], acc[m2][n2], 0, 0, 0);
    }
    __syncthreads();
  }

#pragma unroll
  for (int m2 = 0; m2 < 4; ++m2)
#pragma unroll
    for (int n2 = 0; n2 < 2; ++n2)
#pragma unroll
      for (int r = 0; r < 4; ++r) {
        int row = m0 + wm * 64 + m2 * 16 + (lane >> 4) * 4 + r;
        int col = n0 + wn * 32 + n2 * 16 + (lane & 15);
        float v = acc[m2][n2][r] + bias[col];
        if (GELU_) v = gelu_exact(v);
        if (RESID) v += resid[(size_t)row * N + col];
        size_t o = (size_t)row * N + col;
        if (outb) outb[o] = f2bf(v);
        if (outf) outf[o] = v;
      }
}

// ---------------------------------------------------------------------------
extern "C" void kernel_launch(void* const* d_in, const int* in_sizes, int n_in,
                              void* d_out, int out_size, void* d_ws, size_t ws_size,
                              hipStream_t stream) {
  (void)in_sizes; (void)n_in; (void)out_size; (void)ws_size;
  const float* x      = (const float*)d_in[0];
  const float* il1_w1 = (const float*)d_in[1];
  const float* il1_b1 = (const float*)d_in[2];
  const float* il1_w2 = (const float*)d_in[3];
  const float* il1_b2 = (const float*)d_in[4];
  const float* fc_w   = (const float*)d_in[5];
  const float* fc_b   = (const float*)d_in[6];
  const float* ol1_w1 = (const float*)d_in[7];
  const float* ol1_b1 = (const float*)d_in[8];
  const float* ol1_w2 = (const float*)d_in[9];
  const float* ol1_b2 = (const float*)d_in[10];
  const float* il2_w1 = (const float*)d_in[11];
  const float* il2_b1 = (const float*)d_in[12];
  const float* il2_w2 = (const float*)d_in[13];
  const float* il2_b2 = (const float*)d_in[14];
  const float* ol2_w1 = (const float*)d_in[15];
  const float* ol2_b1 = (const float*)d_in[16];
  const float* ol2_w2 = (const float*)d_in[17];
  const float* ol2_b2 = (const float*)d_in[18];

  char* ws = (char*)d_ws;
  const size_t SZ = 16384ull * 192 * 2;  // one bf16 [16384,192] tensor = 6291456 B
  unsigned short* xbf  = (unsigned short*)(ws);            // x hi (bf16) — also GEMM input
  unsigned short* t13  = (unsigned short*)(ws + SZ);       // t1 then t3
  unsigned short* hbuf = (unsigned short*)(ws + 2 * SZ);   // h
  unsigned short* t2   = (unsigned short*)(ws + 3 * SZ);
  unsigned short* x1b  = (unsigned short*)(ws + 4 * SZ);
  unsigned short* catg = (unsigned short*)(ws + 5 * SZ);   // cat [16384,384] then g [16384,192]
  float*          x1f  = (float*)(ws + 7 * SZ);            // x1 f32
  unsigned short* uv   = (unsigned short*)(ws + 9 * SZ);   // xlo early; u then v [16384,768] later
  unsigned short* xlo  = uv;                               // x lo (bf16) — dead once simtopk done
  int*            graph = (int*)(ws + 13 * SZ);

  conv_kernel<<<3072, 256, 0, stream>>>(x, xbf, xlo);
  simtopk_kernel<<<dim3(32, 16), 512, 0, stream>>>(xbf, xlo, graph);
  // il1: t1 = gelu(x@w1^T+b1); h = t1@w2^T+b2
  gemm_kernel<true,  false><<<dim3(128, 3), 256, 0, stream>>>(xbf, il1_w1, il1_b1, nullptr, t13, nullptr, 192, 192);
  gemm_kernel<false, false><<<dim3(128, 3), 256, 0, stream>>>(t13, il1_w2, il1_b2, nullptr, hbuf, nullptr, 192, 192);
  agg_kernel<<<4096, 256, 0, stream>>>(hbuf, graph, catg);
  // t2 = gelu(cat@fc^T+fc_b)
  gemm_kernel<true,  false><<<dim3(128, 3), 256, 0, stream>>>(catg, fc_w, fc_b, nullptr, t2, nullptr, 192, 384);
  // ol1: t3 = gelu(t2@w1^T+b1); x1 = t3@w2^T+b2 + x
  gemm_kernel<true,  false><<<dim3(128, 3), 256, 0, stream>>>(t2, ol1_w1, ol1_b1, nullptr, t13, nullptr, 192, 192);
  gemm_kernel<false, true ><<<dim3(128, 3), 256, 0, stream>>>(t13, ol1_w2, ol1_b2, x, x1b, x1f, 192, 192);
  // il2: u = gelu(x1@w1^T+b1); g = gelu(u@w2^T+b2)  (external gelu fused)
  gemm_kernel<true,  false><<<dim3(128, 12), 256, 0, stream>>>(x1b, il2_w1, il2_b1, nullptr, uv, nullptr, 768, 192);
  gemm_kernel<true,  false><<<dim3(128, 3), 256, 0, stream>>>(uv, il2_w2, il2_b2, nullptr, catg, nullptr, 192, 768);
  // ol2: v = gelu(g@w1^T+b1); out = v@w2^T+b2 + x1
  gemm_kernel<true,  false><<<dim3(128, 12), 256, 0, stream>>>(catg, ol2_w1, ol2_b1, nullptr, uv, nullptr, 768, 192);
  gemm_kernel<false, true ><<<dim3(128, 3), 256, 0, stream>>>(uv, ol2_w2, ol2_b2, x1f, nullptr, (float*)d_out, 192, 768);
}

// Round 8
// 241.628 us; speedup vs baseline: 1.1026x; 1.1026x over previous
//
#include <hip/hip_runtime.h>
#include <hip/hip_bf16.h>
#include <math.h>

#define DEVINL __device__ __forceinline__

typedef __attribute__((ext_vector_type(4))) float f32x4;
typedef __attribute__((ext_vector_type(8))) short s16x8;

DEVINL unsigned short f2bf(float f) {
  union { float f; unsigned u; } v; v.f = f;
  unsigned r = v.u + 0x7FFFu + ((v.u >> 16) & 1u);   // round-to-nearest-even
  return (unsigned short)(r >> 16);
}
DEVINL float bf2f(unsigned short s) {
  union { unsigned u; float f; } v; v.u = ((unsigned)s) << 16;
  return v.f;
}
DEVINL float gelu_exact(float x) {
  return 0.5f * x * (1.0f + erff(x * 0.70710678118654752f));
}

// ---------------------------------------------------------------------------
// x (f32) -> bf16 hi + bf16 lo (split for fp32-class MFMA sim)
// ---------------------------------------------------------------------------
__global__ __launch_bounds__(256) void conv_kernel(const float* __restrict__ x,
                                                   unsigned short* __restrict__ xh,
                                                   unsigned short* __restrict__ xl) {
  int i = blockIdx.x * 256 + threadIdx.x;   // float4 units, grid sized exactly
  float4 v = ((const float4*)x)[i];
  float f[4] = {v.x, v.y, v.z, v.w};
  unsigned short h[4], l[4];
#pragma unroll
  for (int j = 0; j < 4; ++j) {
    h[j] = f2bf(f[j]);
    l[j] = f2bf(f[j] - bf2f(h[j]));
  }
  uint2 uh, ul;
  uh.x = (unsigned)h[0] | ((unsigned)h[1] << 16);
  uh.y = (unsigned)h[2] | ((unsigned)h[3] << 16);
  ul.x = (unsigned)l[0] | ((unsigned)l[1] << 16);
  ul.y = (unsigned)l[2] | ((unsigned)l[3] << 16);
  ((uint2*)xh)[i] = uh;
  ((uint2*)xl)[i] = ul;
}

// ---------------------------------------------------------------------------
// Weight pre-conversion: 9 f32 matrices -> bf16, one launch.
// ---------------------------------------------------------------------------
struct WArgs {
  const float* s[9];
  unsigned short* d[9];
  int n4[9];            // element count / 4
};
__global__ __launch_bounds__(256) void wconv_kernel(WArgs a) {
  int seg = blockIdx.y;
  int i = blockIdx.x * 256 + threadIdx.x;
  if (i >= a.n4[seg]) return;
  float4 v = ((const float4*)a.s[seg])[i];
  float f[4] = {v.x, v.y, v.z, v.w};
  uint2 u;
  u.x = (unsigned)f2bf(f[0]) | ((unsigned)f2bf(f[1]) << 16);
  u.y = (unsigned)f2bf(f[2]) | ((unsigned)f2bf(f[3]) << 16);
  ((uint2*)a.d[seg])[i] = u;
}

// ---------------------------------------------------------------------------
// Fused sim = x@x^T (split-bf16, 3 MFMA passes) + top-9 per row.
// R7 post-mortem: 102us was NOT spill (2.3MB extra write = ~2 regs once) —
// it's VALU (52%: branchy insert + simt LDS roundtrip) + 4.3x L2 re-fetch
// (FETCH 54.8MB vs 12.6MB input; batch working set sprays across XCDs).
// R8: (1) SWAPPED MFMA operands: mfma(colFrag,rowFrag) puts the x-row at
// C/D col=lane&15 -> each lane owns 4 cols of ONE row per tile -> scan
// fully in-register, simt buffer deleted. (2) Bijective XCD swizzle: 64
// consecutive work-ids (2 batches, 3.1MB) per XCD -> L2-resident.
// ---------------------------------------------------------------------------
__global__ __launch_bounds__(512)
#if __has_attribute(amdgpu_waves_per_eu)
__attribute__((amdgpu_waves_per_eu(4, 4)))
#endif
void simtopk_kernel(const unsigned short* __restrict__ xh,
                    const unsigned short* __restrict__ xl,
                    int* __restrict__ graph) {
  const int tid  = threadIdx.x;
  const int lane = tid & 63;
  const int w    = tid >> 6;
  const int wm   = w >> 2, wn = w & 3;

  // XCD swizzle: hw linear id -> contiguous work chunk per XCD (512%8==0).
  const int lin  = blockIdx.y * 32 + blockIdx.x;
  const int work = (lin & 7) * 64 + (lin >> 3);
  const int rb   = work & 31;        // 32 rows each
  const int b    = work >> 5;

  __shared__ __align__(16) char smem[49152];
  unsigned short* colsH = (unsigned short*)smem;            // [64][192] swizzled, 24576B
  unsigned short* colsL = (unsigned short*)(smem + 24576);  // [64][192]
  // merge-phase aliases (cols dead by then):
  float* Lv = (float*)smem;                                 // [32*16][9] f32
  int*   Li = (int*)(smem + 18432);                         // [32*16][9]
  float* Mv = (float*)(smem + 36864);                       // [128][9] f32
  int*   Mi = (int*)(smem + 41472);                         // [128][9]

  const unsigned short* xhb = xh + (size_t)b * (1024 * 192);
  const unsigned short* xlb = xl + (size_t)b * (1024 * 192);

  // Row fragments (B-operand) -> registers, loaded once. 48 VGPR.
  s16x8 ah[6], al[6];
#pragma unroll
  for (int ks = 0; ks < 6; ++ks) {
    int r = rb * 32 + wm * 16 + (lane & 15);
    size_t off = (size_t)r * 192 + ks * 32 + (lane >> 4) * 8;
    ah[ks] = *(const s16x8*)(xhb + off);
    al[ks] = *(const s16x8*)(xlb + off);
  }

  // Stage col tile ct (64 rows x 192) into LDS. Source pre-swizzled
  // (chunk ^= row&7), LDS dest linear (global_load_lds constraint).
  auto stage = [&](int ct) {
#pragma unroll
    for (int i = 0; i < 3; ++i) {
      int c = tid + i * 512;                 // 16B-chunk id, 0..1535
      int row = c / 24, cc = c - row * 24;
      size_t goff = (size_t)(ct * 64 + row) * 192 + (size_t)((cc ^ (row & 7)) * 8);
      unsigned short* dstH = colsH + (size_t)c * 8;   // wave-uniform base + lane*16B
      unsigned short* dstL = colsL + (size_t)c * 8;
      __builtin_amdgcn_global_load_lds((const __attribute__((address_space(1))) void*)(xhb + goff),
                                       (__attribute__((address_space(3))) void*)dstH, 16, 0, 0);
      __builtin_amdgcn_global_load_lds((const __attribute__((address_space(1))) void*)(xlb + goff),
                                       (__attribute__((address_space(3))) void*)dstL, 16, 0, 0);
    }
  };

  float tv[9]; int tix[9];
#pragma unroll
  for (int k = 0; k < 9; ++k) { tv[k] = -3.0e38f; tix[k] = 1 << 30; }

  stage(0);
  __syncthreads();

  for (int ct = 0; ct < 16; ++ct) {
    f32x4 a0 = 0, a1 = 0, a2 = 0;

#pragma unroll
    for (int ks = 0; ks < 6; ++ks) {
      const int chk = ks * 4 + (lane >> 4);
      const int rc  = wn * 16 + (lane & 15);           // tile-col index (A-operand m)
      const int si  = rc * 192 + ((chk ^ (rc & 7)) * 8);
      s16x8 bh = *(const s16x8*)&colsH[si];
      s16x8 bl = *(const s16x8*)&colsL[si];
      // A=cols, B=rows: D[m=col][n=row]; lane&15 = n = row (lane-local row!)
      a0 = __builtin_amdgcn_mfma_f32_16x16x32_bf16(bh, ah[ks], a0, 0, 0, 0);  // hi.hi
      a1 = __builtin_amdgcn_mfma_f32_16x16x32_bf16(bl, ah[ks], a1, 0, 0, 0);  // lo_col.hi_row
      a2 = __builtin_amdgcn_mfma_f32_16x16x32_bf16(bh, al[ks], a2, 0, 0, 0);  // hi_col.lo_row
    }
    __syncthreads();             // all waves done reading cols

    if (ct < 15) stage(ct + 1);  // async DMA (overwrites cols) hidden under scan

    // in-register scan: lane's row = wm*16+(lane&15); cols = wn*16+(lane>>4)*4+reg
    {
      int cbase = ct * 64 + wn * 16 + (lane >> 4) * 4;
#pragma unroll
      for (int r = 0; r < 4; ++r) {
        float v = a0[r] + a1[r] + a2[r];
        int   c = cbase + r;
        if (v > tv[8]) {   // strict: ascending c keeps lower index first on ties
          tv[8] = v; tix[8] = c;
#pragma unroll
          for (int s = 8; s > 0; --s) {
            if (tv[s] > tv[s - 1]) {
              float fv = tv[s]; tv[s] = tv[s - 1]; tv[s - 1] = fv;
              int   fi = tix[s]; tix[s] = tix[s - 1]; tix[s - 1] = fi;
            }
          }
        }
      }
    }
    __syncthreads();   // staged loads drained (vmcnt(0) at barrier) before next MFMA
  }

  // dump per-thread lists: row-major [row][16 lists] (cols region dead now)
  {
    int rowloc  = wm * 16 + (lane & 15);     // 0..31
    int listid  = wn * 4 + (lane >> 4);      // 0..15
    int lbase   = (rowloc * 16 + listid) * 9;
#pragma unroll
    for (int k = 0; k < 9; ++k) { Lv[lbase + k] = tv[k]; Li[lbase + k] = tix[k]; }
  }
  __syncthreads();

  // merge stage A: 128 threads, each merges 4 of the 16 lists of its row
  if (tid < 128) {
    int r = tid >> 2, p = tid & 3;
    float fv[9]; int fi[9];
#pragma unroll
    for (int k = 0; k < 9; ++k) { fv[k] = -3.0e38f; fi[k] = 1 << 30; }
    for (int s4 = 0; s4 < 4; ++s4) {
      int base = (r * 16 + p * 4 + s4) * 9;
#pragma unroll
      for (int k = 0; k < 9; ++k) {
        float v = Lv[base + k]; int c = Li[base + k];
        bool better = (v > fv[8]) || (v == fv[8] && c < fi[8]);
        if (better) {
          fv[8] = v; fi[8] = c;
#pragma unroll
          for (int s = 8; s > 0; --s) {
            bool up = (fv[s] > fv[s - 1]) || (fv[s] == fv[s - 1] && fi[s] < fi[s - 1]);
            if (up) {
              float a = fv[s]; fv[s] = fv[s - 1]; fv[s - 1] = a;
              int  ii = fi[s]; fi[s] = fi[s - 1]; fi[s - 1] = ii;
            }
          }
        }
      }
    }
#pragma unroll
    for (int k = 0; k < 9; ++k) { Mv[tid * 9 + k] = fv[k]; Mi[tid * 9 + k] = fi[k]; }
  }
  __syncthreads();

  // merge stage B: 32 threads, one per row, merge 4 partials -> graph
  if (tid < 32) {
    float fv[9]; int fi[9];
#pragma unroll
    for (int k = 0; k < 9; ++k) { fv[k] = -3.0e38f; fi[k] = 1 << 30; }
    for (int p = 0; p < 4; ++p) {
      int base = (tid * 4 + p) * 9;
#pragma unroll
      for (int k = 0; k < 9; ++k) {
        float v = Mv[base + k]; int c = Mi[base + k];
        bool better = (v > fv[8]) || (v == fv[8] && c < fi[8]);
        if (better) {
          fv[8] = v; fi[8] = c;
#pragma unroll
          for (int s = 8; s > 0; --s) {
            bool up = (fv[s] > fv[s - 1]) || (fv[s] == fv[s - 1] && fi[s] < fi[s - 1]);
            if (up) {
              float a = fv[s]; fv[s] = fv[s - 1]; fv[s - 1] = a;
              int  ii = fi[s]; fi[s] = fi[s - 1]; fi[s - 1] = ii;
            }
          }
        }
      }
    }
    int* gout = graph + ((size_t)b * 1024 + rb * 32 + tid) * 9;
#pragma unroll
    for (int k = 0; k < 9; ++k) gout[k] = fi[k];
  }
}

// ---------------------------------------------------------------------------
// Gather-max aggregation + interleave: cat[...,2c]=h, cat[...,2c+1]=max_k(h[nbr]-h)
// ---------------------------------------------------------------------------
__global__ __launch_bounds__(256) void agg_kernel(const unsigned short* __restrict__ h,
                                                  const int* __restrict__ graph,
                                                  unsigned short* __restrict__ cat) {
  int gid  = blockIdx.x * 4 + (threadIdx.x >> 6);
  int lane = threadIdx.x & 63;
  int b = gid >> 10;
  int n = gid & 1023;
  const unsigned short* hb = h + (size_t)b * (1024 * 192);
  const int* g = graph + (size_t)gid * 9;
  float hn[3];
#pragma unroll
  for (int j = 0; j < 3; ++j) hn[j] = bf2f(hb[(size_t)n * 192 + lane + j * 64]);
  float ag[3] = {-3.0e38f, -3.0e38f, -3.0e38f};
  for (int k = 0; k < 9; ++k) {
    int idx = g[k];
#pragma unroll
    for (int j = 0; j < 3; ++j) {
      float v = bf2f(hb[(size_t)idx * 192 + lane + j * 64]) - hn[j];
      ag[j] = fmaxf(ag[j], v);
    }
  }
  unsigned* crow = (unsigned*)cat + (size_t)gid * 192;
#pragma unroll
  for (int j = 0; j < 3; ++j) {
    int c = lane + j * 64;
    crow[c] = (unsigned)f2bf(hn[j]) | ((unsigned)f2bf(ag[j]) << 16);
  }
}

// ---------------------------------------------------------------------------
// NT GEMM: out[m,n] = epi( sum_k A[m,k]*W[n,k] + bias[n] )
// A bf16 [M,K], W bf16 [N,K] (pre-converted). BM=128 BN=64 BK=64.
// Both operands staged via global_load_lds with both-sides XOR swizzle
// (rows are 128B -> unswizzled reads would be a 16-way bank conflict).
// LDS[row][s8] = G[row][s8 ^ (row&7)]; read G[row][kc] at LDS[row][kc^(row&7)].
// ---------------------------------------------------------------------------
template <bool GELU_, bool RESID>
__global__ __launch_bounds__(256) void gemm_kernel(const unsigned short* __restrict__ A,
                                                   const unsigned short* __restrict__ W,
                                                   const float* __restrict__ bias,
                                                   const float* __restrict__ resid,
                                                   unsigned short* __restrict__ outb,
                                                   float* __restrict__ outf,
                                                   int N, int K) {
  __shared__ unsigned short As[2][128 * 64];
  __shared__ unsigned short Ws[2][64 * 64];

  const int tid  = threadIdx.x;
  const int lane = tid & 63;
  const int w    = tid >> 6;
  const int m0   = blockIdx.x * 128;
  const int n0   = blockIdx.y * 64;

  auto stageA = [&](int buf, int kt) {
#pragma unroll
    for (int i = 0; i < 4; ++i) {
      int chunk = w * 4 + i;                           // 1KB chunk = 8 rows
      int row = chunk * 8 + (lane >> 3);               // 0..127
      const unsigned short* src = A + (size_t)(m0 + row) * K + kt * 64
                                    + (((lane & 7) ^ (row & 7)) * 8);
      unsigned short* dst = &As[buf][chunk * 512];     // wave-uniform base
      __builtin_amdgcn_global_load_lds((const __attribute__((address_space(1))) void*)src,
                                       (__attribute__((address_space(3))) void*)dst, 16, 0, 0);
    }
  };
  auto stageW = [&](int buf, int kt) {
#pragma unroll
    for (int i = 0; i < 2; ++i) {
      int chunk = w * 2 + i;                           // 0..7
      int row = chunk * 8 + (lane >> 3);               // 0..63
      const unsigned short* src = W + (size_t)(n0 + row) * K + kt * 64
                                    + (((lane & 7) ^ (row & 7)) * 8);
      unsigned short* dst = &Ws[buf][chunk * 512];
      __builtin_amdgcn_global_load_lds((const __attribute__((address_space(1))) void*)src,
                                       (__attribute__((address_space(3))) void*)dst, 16, 0, 0);
    }
  };

  stageA(0, 0);
  stageW(0, 0);
  __syncthreads();

  const int wm = w >> 1, wn = w & 1;
  f32x4 acc[4][2];
#pragma unroll
  for (int a = 0; a < 4; ++a)
#pragma unroll
    for (int c = 0; c < 2; ++c) acc[a][c] = 0;

  const int nk = K >> 6;
  for (int kt = 0; kt < nk; ++kt) {
    const int cur = kt & 1;
    if (kt + 1 < nk) { stageA(cur ^ 1, kt + 1); stageW(cur ^ 1, kt + 1); }
#pragma unroll
    for (int ks = 0; ks < 2; ++ks) {
      const int kc = ks * 4 + (lane >> 4);             // 16B k-chunk id
      s16x8 af[4], bfr[2];
#pragma unroll
      for (int m2 = 0; m2 < 4; ++m2) {
        int row = wm * 64 + m2 * 16 + (lane & 15);
        af[m2] = *(const s16x8*)&As[cur][row * 64 + ((kc ^ (row & 7)) * 8)];
      }
#pragma unroll
      for (int n2 = 0; n2 < 2; ++n2) {
        int rw = wn * 32 + n2 * 16 + (lane & 15);
        bfr[n2] = *(const s16x8*)&Ws[cur][rw * 64 + ((kc ^ (rw & 7)) * 8)];
      }
#pragma unroll
      for (int m2 = 0; m2 < 4; ++m2)
#pragma unroll
        for (int n2 = 0; n2 < 2; ++n2)
          acc[m2][n2] = __builtin_amdgcn_mfma_f32_16x16x32_bf16(af[m2], bfr[n2], acc[m2][n2], 0, 0, 0);
    }
    __syncthreads();
  }

#pragma unroll
  for (int m2 = 0; m2 < 4; ++m2)
#pragma unroll
    for (int n2 = 0; n2 < 2; ++n2)
#pragma unroll
      for (int r = 0; r < 4; ++r) {
        int row = m0 + wm * 64 + m2 * 16 + (lane >> 4) * 4 + r;
        int col = n0 + wn * 32 + n2 * 16 + (lane & 15);
        float v = acc[m2][n2][r] + bias[col];
        if (GELU_) v = gelu_exact(v);
        if (RESID) v += resid[(size_t)row * N + col];
        size_t o = (size_t)row * N + col;
        if (outb) outb[o] = f2bf(v);
        if (outf) outf[o] = v;
      }
}

// ---------------------------------------------------------------------------
extern "C" void kernel_launch(void* const* d_in, const int* in_sizes, int n_in,
                              void* d_out, int out_size, void* d_ws, size_t ws_size,
                              hipStream_t stream) {
  (void)in_sizes; (void)n_in; (void)out_size; (void)ws_size;
  const float* x      = (const float*)d_in[0];
  const float* il1_w1 = (const float*)d_in[1];
  const float* il1_b1 = (const float*)d_in[2];
  const float* il1_w2 = (const float*)d_in[3];
  const float* il1_b2 = (const float*)d_in[4];
  const float* fc_w   = (const float*)d_in[5];
  const float* fc_b   = (const float*)d_in[6];
  const float* ol1_w1 = (const float*)d_in[7];
  const float* ol1_b1 = (const float*)d_in[8];
  const float* ol1_w2 = (const float*)d_in[9];
  const float* ol1_b2 = (const float*)d_in[10];
  const float* il2_w1 = (const float*)d_in[11];
  const float* il2_b1 = (const float*)d_in[12];
  const float* il2_w2 = (const float*)d_in[13];
  const float* il2_b2 = (const float*)d_in[14];
  const float* ol2_w1 = (const float*)d_in[15];
  const float* ol2_b1 = (const float*)d_in[16];
  const float* ol2_w2 = (const float*)d_in[17];
  const float* ol2_b2 = (const float*)d_in[18];

  char* ws = (char*)d_ws;
  const size_t SZ = 16384ull * 192 * 2;  // one bf16 [16384,192] tensor = 6291456 B
  unsigned short* xbf  = (unsigned short*)(ws);            // x hi (bf16) — also GEMM input
  unsigned short* t13  = (unsigned short*)(ws + SZ);       // t1 then t3
  unsigned short* hbuf = (unsigned short*)(ws + 2 * SZ);   // h
  unsigned short* t2   = (unsigned short*)(ws + 3 * SZ);
  unsigned short* x1b  = (unsigned short*)(ws + 4 * SZ);
  unsigned short* catg = (unsigned short*)(ws + 5 * SZ);   // cat [16384,384] then g [16384,192]
  float*          x1f  = (float*)(ws + 7 * SZ);            // x1 f32
  unsigned short* uv   = (unsigned short*)(ws + 9 * SZ);   // xlo early; u then v [16384,768] later
  unsigned short* xlo  = uv;                               // x lo (bf16) — dead once simtopk done
  int*            graph = (int*)(ws + 13 * SZ);            // 576KB
  unsigned short* wb   = (unsigned short*)(ws + 13 * SZ + (1 << 20));  // bf16 weights, 1.6MB

  // bf16 weight pointers (element offsets into wb)
  unsigned short* il1_w1b = wb;
  unsigned short* il1_w2b = wb + 36864;
  unsigned short* fcb     = wb + 73728;
  unsigned short* ol1_w1b = wb + 147456;
  unsigned short* ol1_w2b = wb + 184320;
  unsigned short* il2_w1b = wb + 221184;
  unsigned short* il2_w2b = wb + 368640;
  unsigned short* ol2_w1b = wb + 516096;
  unsigned short* ol2_w2b = wb + 663552;

  WArgs wa;
  wa.s[0] = il1_w1; wa.d[0] = il1_w1b; wa.n4[0] = 36864 / 4;
  wa.s[1] = il1_w2; wa.d[1] = il1_w2b; wa.n4[1] = 36864 / 4;
  wa.s[2] = fc_w;   wa.d[2] = fcb;     wa.n4[2] = 73728 / 4;
  wa.s[3] = ol1_w1; wa.d[3] = ol1_w1b; wa.n4[3] = 36864 / 4;
  wa.s[4] = ol1_w2; wa.d[4] = ol1_w2b; wa.n4[4] = 36864 / 4;
  wa.s[5] = il2_w1; wa.d[5] = il2_w1b; wa.n4[5] = 147456 / 4;
  wa.s[6] = il2_w2; wa.d[6] = il2_w2b; wa.n4[6] = 147456 / 4;
  wa.s[7] = ol2_w1; wa.d[7] = ol2_w1b; wa.n4[7] = 147456 / 4;
  wa.s[8] = ol2_w2; wa.d[8] = ol2_w2b; wa.n4[8] = 147456 / 4;

  conv_kernel<<<3072, 256, 0, stream>>>(x, xbf, xlo);
  wconv_kernel<<<dim3(144, 9), 256, 0, stream>>>(wa);
  simtopk_kernel<<<dim3(32, 16), 512, 0, stream>>>(xbf, xlo, graph);
  // il1: t1 = gelu(x@w1^T+b1); h = t1@w2^T+b2
  gemm_kernel<true,  false><<<dim3(128, 3), 256, 0, stream>>>(xbf, il1_w1b, il1_b1, nullptr, t13, nullptr, 192, 192);
  gemm_kernel<false, false><<<dim3(128, 3), 256, 0, stream>>>(t13, il1_w2b, il1_b2, nullptr, hbuf, nullptr, 192, 192);
  agg_kernel<<<4096, 256, 0, stream>>>(hbuf, graph, catg);
  // t2 = gelu(cat@fc^T+fc_b)
  gemm_kernel<true,  false><<<dim3(128, 3), 256, 0, stream>>>(catg, fcb, fc_b, nullptr, t2, nullptr, 192, 384);
  // ol1: t3 = gelu(t2@w1^T+b1); x1 = t3@w2^T+b2 + x
  gemm_kernel<true,  false><<<dim3(128, 3), 256, 0, stream>>>(t2, ol1_w1b, ol1_b1, nullptr, t13, nullptr, 192, 192);
  gemm_kernel<false, true ><<<dim3(128, 3), 256, 0, stream>>>(t13, ol1_w2b, ol1_b2, x, x1b, x1f, 192, 192);
  // il2: u = gelu(x1@w1^T+b1); g = gelu(u@w2^T+b2)  (external gelu fused)
  gemm_kernel<true,  false><<<dim3(128, 12), 256, 0, stream>>>(x1b, il2_w1b, il2_b1, nullptr, uv, nullptr, 768, 192);
  gemm_kernel<true,  false><<<dim3(128, 3), 256, 0, stream>>>(uv, il2_w2b, il2_b2, nullptr, catg, nullptr, 192, 768);
  // ol2: v = gelu(g@w1^T+b1); out = v@w2^T+b2 + x1
  gemm_kernel<true,  false><<<dim3(128, 12), 256, 0, stream>>>(catg, ol2_w1b, ol2_b1, nullptr, uv, nullptr, 768, 192);
  gemm_kernel<false, true ><<<dim3(128, 3), 256, 0, stream>>>(uv, ol2_w2b, ol2_b2, x1f, nullptr, (float*)d_out, 192, 768);
}